// Round 13
// baseline (119.339 us; speedup 1.0000x reference)
//
#include <hip/hip_runtime.h>

typedef unsigned short u16;
typedef unsigned int   u32;
typedef __attribute__((ext_vector_type(8))) short bf8_t;   // 8 bf16 (4 VGPR)
typedef __attribute__((ext_vector_type(4))) float f4_t;

#define SEQ   1024
#define NH    16
#define DH    128
#define BATCH 4
#define MROWS 4096      // BATCH*SEQ
#define FDIM  2048      // NH*DH

__device__ __forceinline__ u16 f2bf(float f) {
  union { float f; u32 u; } v; v.f = f;
  u32 u = v.u;
  u += 0x7fffu + ((u >> 16) & 1u);   // RNE
  return (u16)(u >> 16);
}

// ---------------- kernel P: bf16 convert + RoPE tables (merged) ------------
__global__ __launch_bounds__(256) void prep(
    const float* __restrict__ x,  const float* __restrict__ wq,
    const float* __restrict__ wk, const float* __restrict__ wv,
    const float* __restrict__ wo,
    u16* __restrict__ xb, u16* __restrict__ wqb, u16* __restrict__ wkb,
    u16* __restrict__ wvb, u16* __restrict__ wob,
    float* __restrict__ cosT, float* __restrict__ sinT) {
  const int gb = blockIdx.x;
  if (gb < 768) {
    int i = gb * 256 + threadIdx.x;   // 0..196607
    const float* s; u16* d; int o;
    if      (i <  65536) { s = x;  d = xb;  o = i; }
    else if (i <  98304) { s = wq; d = wqb; o = i - 65536; }
    else if (i < 131072) { s = wk; d = wkb; o = i - 98304; }
    else if (i < 163840) { s = wv; d = wvb; o = i - 131072; }
    else                 { s = wo; d = wob; o = i - 163840; }
    const f4_t* sp = reinterpret_cast<const f4_t*>(s + (size_t)o * 8);
    f4_t a = sp[0], b = sp[1];
    bf8_t pk;
#pragma unroll
    for (int j = 0; j < 4; ++j) { pk[j] = (short)f2bf(a[j]); pk[4 + j] = (short)f2bf(b[j]); }
    *reinterpret_cast<bf8_t*>(d + (size_t)o * 8) = pk;
  } else {
    int i = (gb - 768) * 256 + threadIdx.x;      // 65536 = 64*1024
    int p = i >> 10, s = i & 1023;               // [p][s]
    float ef = (float)(2 * p) / 128.0f;
    float angf = (float)pow(10000.0, (double)ef);
    float thf  = (float)s * angf;
    cosT[i] = cosf(thf);
    sinT[i] = sinf(thf);
  }
}

// ---------------- kernel A: fused QKV projection + RoPE --------------------
// One block per (mt,nt): x-tile staged ONCE, then mat loop {q,k,v} staging
// only w. q,k: RoPE'd [bh][s][d]; v: transposed to vT_g[bh][dv][s].
__device__ __forceinline__ void stage_tile(const u16* __restrict__ src,
                                           u16* __restrict__ dst, int tid) {
#pragma unroll
  for (int i = 0; i < 4; ++i) {
    int idx = tid + i * 256;            // 0..1023
    int row = idx >> 4, e0 = (idx & 15) * 8;
    int hw = ((row << 7) | e0) ^ ((row & 7) << 3);
    *reinterpret_cast<bf8_t*>(&dst[hw]) =
        *reinterpret_cast<const bf8_t*>(src + (size_t)row * 128 + e0);
  }
}

__global__ __launch_bounds__(256) void qkv_rope(
    const u16* __restrict__ xb,
    const u16* __restrict__ wqb, const u16* __restrict__ wkb,
    const u16* __restrict__ wvb,
    const float* __restrict__ cosT, const float* __restrict__ sinT,
    u16* __restrict__ qo, u16* __restrict__ ko, u16* __restrict__ vo) {
  __shared__ __align__(16) u16 a_lds[64 * 128];
  __shared__ __align__(16) u16 b_lds[64 * 128];
  const int tid = threadIdx.x;
  const int mt = blockIdx.x;            // 0..63
  const int nt = blockIdx.y;            // 0..31
  const int m0 = mt * 64, n0 = nt * 64;

  stage_tile(xb + (size_t)m0 * 128, a_lds, tid);

  const int lane = tid & 63, wid = tid >> 6;
  const int wr = wid >> 1, wc = wid & 1;
  const int g = lane >> 4, c16 = lane & 15;

#pragma unroll
  for (int mat = 0; mat < 3; ++mat) {
    if (mat) __syncthreads();           // prior MFMA done with b_lds
    const u16* w = (mat == 0) ? wqb : ((mat == 1) ? wkb : wvb);
    stage_tile(w + (size_t)n0 * 128, b_lds, tid);
    __syncthreads();

    f4_t acc[2][2];
#pragma unroll
    for (int a = 0; a < 2; ++a)
#pragma unroll
      for (int b = 0; b < 2; ++b) acc[a][b] = (f4_t)0.0f;

#pragma unroll
    for (int kc = 0; kc < 4; ++kc) {
      bf8_t af[2], bf_[2];
#pragma unroll
      for (int fr = 0; fr < 2; ++fr) {
        int row = wr * 32 + fr * 16 + c16;
        int hw = ((row << 7) | (kc * 32 + g * 8)) ^ ((row & 7) << 3);
        af[fr] = *reinterpret_cast<const bf8_t*>(&a_lds[hw]);
      }
#pragma unroll
      for (int fc = 0; fc < 2; ++fc) {
        int row = wc * 32 + fc * 16 + c16;
        int hw = ((row << 7) | (kc * 32 + g * 8)) ^ ((row & 7) << 3);
        bf_[fc] = *reinterpret_cast<const bf8_t*>(&b_lds[hw]);
      }
#pragma unroll
      for (int fr = 0; fr < 2; ++fr)
#pragma unroll
        for (int fc = 0; fc < 2; ++fc)
          acc[fr][fc] = __builtin_amdgcn_mfma_f32_16x16x32_bf16(af[fr], bf_[fc], acc[fr][fc], 0, 0, 0);
    }

    if (mat == 2) {
      // ---- V: transpose via LDS (stride 72), write vT_g coalesced ----
      __syncthreads();                  // all waves done reading a_lds
#pragma unroll
      for (int fr = 0; fr < 2; ++fr)
#pragma unroll
        for (int fc = 0; fc < 2; ++fc)
#pragma unroll
          for (int j = 0; j < 4; ++j) {
            int fcol = wc * 32 + fc * 16 + c16;     // 0..63 (local dv)
            int m = wr * 32 + fr * 16 + g * 4 + j;  // 0..63 (local s)
            a_lds[fcol * 72 + m] = f2bf(acc[fr][fc][j]);
          }
      __syncthreads();
      const int b = mt >> 4, sl0 = m0 & 1023;
      const int hq = nt >> 1, dvb = (nt & 1) * 64;
#pragma unroll
      for (int i = 0; i < 2; ++i) {
        int r = tid >> 2, c0 = ((tid & 3) * 2 + i) * 8;   // r 0..63, c0 0..56
        bf8_t v = *reinterpret_cast<const bf8_t*>(&a_lds[r * 72 + c0]);
        size_t adr = ((size_t)((b * 16 + hq) * 128 + dvb + r)) * 1024 + sl0 + c0;
        *reinterpret_cast<bf8_t*>(vo + adr) = v;
      }
    } else {
      // ---- q/k: RoPE epilogue (tables [p][s], f4 loads) ----
      u16* outp = (mat == 0) ? qo : ko;
#pragma unroll
      for (int fr = 0; fr < 2; ++fr) {
#pragma unroll
        for (int fc = 0; fc < 2; ++fc) {
          int fcol = n0 + wc * 32 + fc * 16 + c16;   // 0..2047
          int h = fcol >> 7, d = fcol & 127, p = d >> 1;
          int m_base = m0 + wr * 32 + fr * 16 + g * 4;
          int b = m_base >> 10, sl_base = m_base & 1023;
          f4_t cv4 = *reinterpret_cast<const f4_t*>(&cosT[p * 1024 + sl_base]);
          f4_t sv4 = *reinterpret_cast<const f4_t*>(&sinT[p * 1024 + sl_base]);
#pragma unroll
          for (int j = 0; j < 4; ++j) {
            float v = acc[fr][fc][j];
            float vx = __shfl_xor(v, 1);
            float cv = cv4[j], sv = sv4[j];
            if (!(lane & 1)) {
              float e_out = v * cv - vx * sv;
              float o_out = v * sv + vx * cv;
              u32 u = (u32)f2bf(e_out) | ((u32)f2bf(o_out) << 16);
              u32 elem = ((u32)((b * 16 + h) * 1024 + (sl_base + j))) * 128 + (u32)d;
              reinterpret_cast<u32*>(outp)[elem >> 1] = u;
            }
          }
        }
      }
    }
  }
}

// ---------------- kernel B: flash attention, 8-wave blocks -----------------
// 512 threads; waves 0..7 cover q-rows p*128 + wid*16 .. +15 (q-tiles 2p,2p+1)
// and SHARE each staged K/V tile. T = 2p+2. Datapath identical to r9/r11.
// Pairing: first 256 blocks p=7..4, second 256 p=0..3 -> co-resident pairs
// sum T = 18. LDS 54.5 KB -> exactly 2 blocks/CU = 16 waves/CU.
__device__ __forceinline__ void stage_kv(const u16* __restrict__ Kp,
                                         const u16* __restrict__ Vt, int t,
                                         int tid, u16* k_lds, u16* vT) {
#pragma unroll
  for (int i = 0; i < 2; ++i) {
    int ck = tid + i * 512;                                    // 0..1023
    int n = ck >> 4, c0 = (ck & 15) * 8;                       // K: 64x128
    bf8_t kv = *reinterpret_cast<const bf8_t*>(Kp + (size_t)(t * 64 + n) * 128 + c0);
    *reinterpret_cast<bf8_t*>(&k_lds[n * 128 + (c0 ^ ((n & 7) << 3))]) = kv;
    int dv = ck >> 3, c1 = (ck & 7) * 8;                       // vT: 128x64
    bf8_t vv = *reinterpret_cast<const bf8_t*>(Vt + (size_t)dv * 1024 + t * 64 + c1);
    *reinterpret_cast<bf8_t*>(&vT[dv * 72 + c1]) = vv;
  }
}

__global__ __launch_bounds__(512, 4) void attn(
    const u16* __restrict__ qw, const u16* __restrict__ kw,
    const u16* __restrict__ vtg, u16* __restrict__ yw) {
  __shared__ __align__(16) u16 k_lds[64 * 128];       // 16 KB, XOR swizzle
  __shared__ __align__(16) u16 vT[160 * 72];          // 22.5 KB (144..159 pad)
  __shared__ __align__(16) u16 p_lds[8][16 * 64];     // 16 KB, per-wave
  const int tid = threadIdx.x, lane = tid & 63, wid = tid >> 6;   // wid 0..7
  const int g = lane >> 4, c16 = lane & 15;
  const int bid = blockIdx.x;                  // 0..511
  const int half = bid >> 8, idx = bid & 255;
  const int bh = idx & 63;                     // bid%8 == bh%8 -> same XCD
  const int ps = idx >> 6;                     // 0..3
  const int p = half ? ps : (7 - ps);          // LPT + positional pairing
  const int T = 2 * p + 2;
  const int b = bh >> 4, h = bh & 15;
  const u16* Qp = qw + (size_t)bh * SEQ * DH;
  const u16* Kp = kw + (size_t)bh * SEQ * DH;
  const u16* Vt = vtg + (size_t)bh * DH * SEQ;
  const float kscale = 0.08838834764831845f * 1.4426950408889634f; // rsqrt(128)*log2e
  const int qrow0 = p * 128 + wid * 16;        // wave's 16 q-rows (global)

  // ones row (dv=128) + zero rows 129..143 (cols 0..63 read)
  {
    int r = 128 + (tid >> 5), c0 = (tid & 31) * 2;
    u16 v = (r == 128) ? (u16)0x3F80 : (u16)0;
    vT[r * 72 + c0] = v;
    vT[r * 72 + c0 + 1] = v;
  }

  bf8_t qf[4];
#pragma unroll
  for (int c = 0; c < 4; ++c)
    qf[c] = *reinterpret_cast<const bf8_t*>(Qp + (size_t)(qrow0 + c16) * 128 + c * 32 + g * 8);

  f4_t yacc[9];                               // [8] = l (ones-column)
#pragma unroll
  for (int f = 0; f < 9; ++f) yacc[f] = (f4_t)0.0f;
  float m_run[4];
#pragma unroll
  for (int j = 0; j < 4; ++j) m_run[j] = -3e38f;

  stage_kv(Kp, Vt, 0, tid, k_lds, vT);
  __syncthreads();

  for (int t = 0; t < T; ++t) {
    // ---- S = Q K^T ----
    f4_t sf[4];
#pragma unroll
    for (int nf = 0; nf < 4; ++nf) sf[nf] = (f4_t)0.0f;
    __builtin_amdgcn_s_setprio(1);
#pragma unroll
    for (int nf = 0; nf < 4; ++nf) {
      int row = nf * 16 + c16;
#pragma unroll
      for (int kc = 0; kc < 4; ++kc) {
        int hw = ((row << 7) | (kc * 32 + g * 8)) ^ ((row & 7) << 3);
        bf8_t kf = *reinterpret_cast<const bf8_t*>(&k_lds[hw]);
        sf[nf] = __builtin_amdgcn_mfma_f32_16x16x32_bf16(qf[kc], kf, sf[nf], 0, 0, 0);
      }
    }
    __builtin_amdgcn_s_setprio(0);

    // ---- causal mask: any key in tile t can exceed the wave's lowest q-row
    // (gate fixed: t*64+64 > qrow0; r12's +48 missed wid%4==3 diagonals) ----
    if (t * 64 + 64 > qrow0) {
#pragma unroll
      for (int nf = 0; nf < 4; ++nf) {
        int keyc = t * 64 + nf * 16 + c16;
#pragma unroll
        for (int j = 0; j < 4; ++j)
          if (keyc > qrow0 + g * 4 + j) sf[nf][j] = -3e38f;
      }
    }

    // ---- defer-max guard: cross-lane work only when needed (tile 0 + rare)
    int chk = 0;
#pragma unroll
    for (int j = 0; j < 4; ++j) {
      float lmx = fmaxf(fmaxf(sf[0][j], sf[1][j]), fmaxf(sf[2][j], sf[3][j]));
      chk |= (lmx > m_run[j] + 32.0f) ? 1 : 0;
    }
    if (__any(chk)) {
      float lm[4];
#pragma unroll
      for (int j = 0; j < 4; ++j) {
        lm[j] = fmaxf(fmaxf(sf[0][j], sf[1][j]), fmaxf(sf[2][j], sf[3][j]));
        lm[j] = fmaxf(lm[j], __shfl_xor(lm[j], 1));
        lm[j] = fmaxf(lm[j], __shfl_xor(lm[j], 2));
        lm[j] = fmaxf(lm[j], __shfl_xor(lm[j], 4));
        lm[j] = fmaxf(lm[j], __shfl_xor(lm[j], 8));
      }
#pragma unroll
      for (int j = 0; j < 4; ++j) {
        float mn = fmaxf(m_run[j], lm[j]);
        float alpha = exp2f((m_run[j] - mn) * kscale);
        m_run[j] = mn;
#pragma unroll
        for (int f = 0; f < 9; ++f) yacc[f][j] *= alpha;
      }
    }

    // ---- P = exp2((S-m)*ks) -> bf16 -> wave-private p_lds ----
#pragma unroll
    for (int nf = 0; nf < 4; ++nf) {
#pragma unroll
      for (int j = 0; j < 4; ++j) {
        float pv = exp2f((sf[nf][j] - m_run[j]) * kscale);
        int q = g * 4 + j, n = nf * 16 + c16;
        int hw = ((q << 6) | n) ^ ((q & 7) << 3);
        p_lds[wid][hw] = f2bf(pv);
      }
    }
    bf8_t pa[2];
#pragma unroll
    for (int cc = 0; cc < 2; ++cc) {
      int hw = ((c16 << 6) | (cc * 32 + g * 8)) ^ ((c16 & 7) << 3);
      pa[cc] = *reinterpret_cast<const bf8_t*>(&p_lds[wid][hw]);
    }

    // ---- y += P V ; l accumulates via ones-column (f=8) ----
    __builtin_amdgcn_s_setprio(1);
#pragma unroll
    for (int f = 0; f < 9; ++f) {
#pragma unroll
      for (int cc = 0; cc < 2; ++cc) {
        bf8_t vf = *reinterpret_cast<const bf8_t*>(&vT[(f * 16 + c16) * 72 + cc * 32 + g * 8]);
        yacc[f] = __builtin_amdgcn_mfma_f32_16x16x32_bf16(pa[cc], vf, yacc[f], 0, 0, 0);
      }
    }
    __builtin_amdgcn_s_setprio(0);

    __syncthreads();                     // everyone done reading k/vT
    if (t + 1 < T) {
      stage_kv(Kp, Vt, t + 1, tid, k_lds, vT);
      __syncthreads();
    }
  }

  // ---- epilogue: l broadcast from c16==0 lane; y /= l; store bf16 ----
  float rl[4];
#pragma unroll
  for (int j = 0; j < 4; ++j) {
    float lv = __shfl(yacc[8][j], lane & 48);
    rl[j] = 1.0f / lv;
  }
#pragma unroll
  for (int f = 0; f < 8; ++f) {
#pragma unroll
    for (int j = 0; j < 4; ++j) {
      float yv = yacc[f][j] * rl[j];
      float yn = __shfl_xor(yv, 1);
      if (!(lane & 1)) {
        int s_ = qrow0 + g * 4 + j;
        int dv = f * 16 + c16;
        u32 u = (u32)f2bf(yv) | ((u32)f2bf(yn) << 16);
        u32 elem = ((u32)(b * 1024 + s_)) * 2048 + (u32)(h * 128 + dv);
        reinterpret_cast<u32*>(yw)[elem >> 1] = u;
      }
    }
  }
}

// ---------------- kernel C: output projection (split-K=2, T14 prefetch) ----
__global__ __launch_bounds__(256) void oproj(
    const u16* __restrict__ yw, const u16* __restrict__ wob,
    float* __restrict__ out) {
  __shared__ __align__(16) u16 a_lds[64 * 64];
  __shared__ __align__(16) u16 b_lds[64 * 64];
  const int tid = threadIdx.x, lane = tid & 63, wid = tid >> 6;
  const int g = lane >> 4, c16 = lane & 15;
  const int wr = wid >> 1, wc = wid & 1;
  const int m0 = blockIdx.x * 64, n0 = blockIdx.y * 64;
  const int z = blockIdx.z;
  const int kt0 = z * 16;
  f4_t acc[2][2];
#pragma unroll
  for (int a = 0; a < 2; ++a)
#pragma unroll
    for (int b = 0; b < 2; ++b) acc[a][b] = (f4_t)0.0f;

  const int srow = tid >> 3, sk0 = (tid & 7) * 8;

  bf8_t areg[2], breg[2];
#pragma unroll
  for (int i = 0; i < 2; ++i) {
    int row = srow + i * 32;
    areg[i] = *reinterpret_cast<const bf8_t*>(yw + (size_t)(m0 + row) * 2048 + kt0 * 64 + sk0);
    breg[i] = *reinterpret_cast<const bf8_t*>(wob + (size_t)(n0 + row) * 2048 + kt0 * 64 + sk0);
  }
#pragma unroll
  for (int i = 0; i < 2; ++i) {
    int row = srow + i * 32;
    int hw = ((row << 6) | sk0) ^ ((row & 7) << 3);
    *reinterpret_cast<bf8_t*>(&a_lds[hw]) = areg[i];
    *reinterpret_cast<bf8_t*>(&b_lds[hw]) = breg[i];
  }
  __syncthreads();

  for (int kt = kt0; kt < kt0 + 16; ++kt) {
    const bool pf = (kt + 1 < kt0 + 16);
    if (pf) {
      int kb = (kt + 1) * 64;
#pragma unroll
      for (int i = 0; i < 2; ++i) {
        int row = srow + i * 32;
        areg[i] = *reinterpret_cast<const bf8_t*>(yw + (size_t)(m0 + row) * 2048 + kb + sk0);
        breg[i] = *reinterpret_cast<const bf8_t*>(wob + (size_t)(n0 + row) * 2048 + kb + sk0);
      }
    }
#pragma unroll
    for (int c = 0; c < 2; ++c) {
      bf8_t af[2], bf_[2];
#pragma unroll
      for (int fr = 0; fr < 2; ++fr) {
        int row = wr * 32 + fr * 16 + c16;
        int hw = ((row << 6) | (c * 32 + g * 8)) ^ ((row & 7) << 3);
        af[fr] = *reinterpret_cast<const bf8_t*>(&a_lds[hw]);
      }
#pragma unroll
      for (int fc = 0; fc < 2; ++fc) {
        int row = wc * 32 + fc * 16 + c16;
        int hw = ((row << 6) | (c * 32 + g * 8)) ^ ((row & 7) << 3);
        bf_[fc] = *reinterpret_cast<const bf8_t*>(&b_lds[hw]);
      }
#pragma unroll
      for (int fr = 0; fr < 2; ++fr)
#pragma unroll
        for (int fc = 0; fc < 2; ++fc)
          acc[fr][fc] = __builtin_amdgcn_mfma_f32_16x16x32_bf16(af[fr], bf_[fc], acc[fr][fc], 0, 0, 0);
    }
    __syncthreads();
    if (pf) {
#pragma unroll
      for (int i = 0; i < 2; ++i) {
        int row = srow + i * 32;
        int hw = ((row << 6) | sk0) ^ ((row & 7) << 3);
        *reinterpret_cast<bf8_t*>(&a_lds[hw]) = areg[i];
        *reinterpret_cast<bf8_t*>(&b_lds[hw]) = breg[i];
      }
      __syncthreads();
    }
  }
#pragma unroll
  for (int fr = 0; fr < 2; ++fr)
#pragma unroll
    for (int fc = 0; fc < 2; ++fc)
#pragma unroll
      for (int j = 0; j < 4; ++j) {
        int m = m0 + wr * 32 + fr * 16 + g * 4 + j;
        int e = n0 + wc * 32 + fc * 16 + c16;
        atomicAdd(&out[(size_t)m * 128 + e], acc[fr][fc][j]);  // 2 addends: exact
      }
}

// ---------------------------------------------------------------------------
extern "C" void kernel_launch(void* const* d_in, const int* in_sizes, int n_in,
                              void* d_out, int out_size, void* d_ws, size_t ws_size,
                              hipStream_t stream) {
  const float* x  = (const float*)d_in[0];
  const float* wq = (const float*)d_in[1];
  const float* wk = (const float*)d_in[2];
  const float* wv = (const float*)d_in[3];
  const float* wo = (const float*)d_in[4];
  float* out = (float*)d_out;

  char* ws = (char*)d_ws;
  const size_t NEED = (512ull << 10) + 4ull * (16ull << 20) + (3ull << 20);
  if (ws_size < NEED) return;
  float* cosT = (float*)ws;                 // [p][s] transposed
  float* sinT = cosT + 64 * 1024;
  u16* qws = (u16*)(ws + (512 << 10));
  u16* kws = qws + (8u << 20);
  u16* vws = kws + (8u << 20);      // vT_g[bh][dv][s]
  u16* yws = vws + (8u << 20);
  u16* xb  = yws + (8u << 20);
  u16* wqb = xb  + (1u << 19);
  u16* wkb = wqb + (1u << 18);
  u16* wvb = wkb + (1u << 18);
  u16* wob = wvb + (1u << 18);

  hipMemsetAsync(d_out, 0, (size_t)out_size * sizeof(float), stream);
  prep<<<1024, 256, 0, stream>>>(x, wq, wk, wv, wo, xb, wqb, wkb, wvb, wob, cosT, sinT);
  qkv_rope<<<dim3(64, 32), 256, 0, stream>>>(xb, wqb, wkb, wvb, cosT, sinT, qws, kws, vws);
  attn<<<512, 512, 0, stream>>>(qws, kws, vws, yws);
  oproj<<<dim3(64, 2, 2), 256, 0, stream>>>(yws, wob, out);
}

// Round 14
// 91.920 us; speedup vs baseline: 1.2983x; 1.2983x over previous
//
#include <hip/hip_runtime.h>

typedef unsigned short u16;
typedef unsigned int   u32;
typedef __attribute__((ext_vector_type(8))) short bf8_t;   // 8 bf16 (4 VGPR)
typedef __attribute__((ext_vector_type(4))) float f4_t;

#define SEQ   1024
#define NH    16
#define DH    128
#define BATCH 4
#define MROWS 4096      // BATCH*SEQ
#define FDIM  2048      // NH*DH

__device__ __forceinline__ u16 f2bf(float f) {
  union { float f; u32 u; } v; v.f = f;
  u32 u = v.u;
  u += 0x7fffu + ((u >> 16) & 1u);   // RNE
  return (u16)(u >> 16);
}

// ---------------- kernel P: bf16 convert + RoPE tables (merged) ------------
__global__ __launch_bounds__(256) void prep(
    const float* __restrict__ x,  const float* __restrict__ wq,
    const float* __restrict__ wk, const float* __restrict__ wv,
    const float* __restrict__ wo,
    u16* __restrict__ xb, u16* __restrict__ wqb, u16* __restrict__ wkb,
    u16* __restrict__ wvb, u16* __restrict__ wob,
    float* __restrict__ cosT, float* __restrict__ sinT) {
  const int gb = blockIdx.x;
  if (gb < 768) {
    int i = gb * 256 + threadIdx.x;   // 0..196607
    const float* s; u16* d; int o;
    if      (i <  65536) { s = x;  d = xb;  o = i; }
    else if (i <  98304) { s = wq; d = wqb; o = i - 65536; }
    else if (i < 131072) { s = wk; d = wkb; o = i - 98304; }
    else if (i < 163840) { s = wv; d = wvb; o = i - 131072; }
    else                 { s = wo; d = wob; o = i - 163840; }
    const f4_t* sp = reinterpret_cast<const f4_t*>(s + (size_t)o * 8);
    f4_t a = sp[0], b = sp[1];
    bf8_t pk;
#pragma unroll
    for (int j = 0; j < 4; ++j) { pk[j] = (short)f2bf(a[j]); pk[4 + j] = (short)f2bf(b[j]); }
    *reinterpret_cast<bf8_t*>(d + (size_t)o * 8) = pk;
  } else {
    int i = (gb - 768) * 256 + threadIdx.x;      // 65536 = 64*1024
    int p = i >> 10, s = i & 1023;               // [p][s]
    float ef = (float)(2 * p) / 128.0f;
    float angf = (float)pow(10000.0, (double)ef);
    float thf  = (float)s * angf;
    cosT[i] = cosf(thf);
    sinT[i] = sinf(thf);
  }
}

// ---------------- kernel A: fused QKV projection + RoPE --------------------
// One block per (mt,nt): x-tile staged ONCE, then mat loop {q,k,v} staging
// only w. q,k: RoPE'd [bh][s][d]; v: transposed to vT_g[bh][dv][s].
__device__ __forceinline__ void stage_tile(const u16* __restrict__ src,
                                           u16* __restrict__ dst, int tid) {
#pragma unroll
  for (int i = 0; i < 4; ++i) {
    int idx = tid + i * 256;            // 0..1023
    int row = idx >> 4, e0 = (idx & 15) * 8;
    int hw = ((row << 7) | e0) ^ ((row & 7) << 3);
    *reinterpret_cast<bf8_t*>(&dst[hw]) =
        *reinterpret_cast<const bf8_t*>(src + (size_t)row * 128 + e0);
  }
}

__global__ __launch_bounds__(256) void qkv_rope(
    const u16* __restrict__ xb,
    const u16* __restrict__ wqb, const u16* __restrict__ wkb,
    const u16* __restrict__ wvb,
    const float* __restrict__ cosT, const float* __restrict__ sinT,
    u16* __restrict__ qo, u16* __restrict__ ko, u16* __restrict__ vo) {
  __shared__ __align__(16) u16 a_lds[64 * 128];
  __shared__ __align__(16) u16 b_lds[64 * 128];
  const int tid = threadIdx.x;
  const int mt = blockIdx.x;            // 0..63
  const int nt = blockIdx.y;            // 0..31
  const int m0 = mt * 64, n0 = nt * 64;

  stage_tile(xb + (size_t)m0 * 128, a_lds, tid);

  const int lane = tid & 63, wid = tid >> 6;
  const int wr = wid >> 1, wc = wid & 1;
  const int g = lane >> 4, c16 = lane & 15;

#pragma unroll
  for (int mat = 0; mat < 3; ++mat) {
    if (mat) __syncthreads();           // prior MFMA done with b_lds
    const u16* w = (mat == 0) ? wqb : ((mat == 1) ? wkb : wvb);
    stage_tile(w + (size_t)n0 * 128, b_lds, tid);
    __syncthreads();

    f4_t acc[2][2];
#pragma unroll
    for (int a = 0; a < 2; ++a)
#pragma unroll
      for (int b = 0; b < 2; ++b) acc[a][b] = (f4_t)0.0f;

#pragma unroll
    for (int kc = 0; kc < 4; ++kc) {
      bf8_t af[2], bf_[2];
#pragma unroll
      for (int fr = 0; fr < 2; ++fr) {
        int row = wr * 32 + fr * 16 + c16;
        int hw = ((row << 7) | (kc * 32 + g * 8)) ^ ((row & 7) << 3);
        af[fr] = *reinterpret_cast<const bf8_t*>(&a_lds[hw]);
      }
#pragma unroll
      for (int fc = 0; fc < 2; ++fc) {
        int row = wc * 32 + fc * 16 + c16;
        int hw = ((row << 7) | (kc * 32 + g * 8)) ^ ((row & 7) << 3);
        bf_[fc] = *reinterpret_cast<const bf8_t*>(&b_lds[hw]);
      }
#pragma unroll
      for (int fr = 0; fr < 2; ++fr)
#pragma unroll
        for (int fc = 0; fc < 2; ++fc)
          acc[fr][fc] = __builtin_amdgcn_mfma_f32_16x16x32_bf16(af[fr], bf_[fc], acc[fr][fc], 0, 0, 0);
    }

    if (mat == 2) {
      // ---- V: transpose via LDS (stride 72), write vT_g coalesced ----
      __syncthreads();                  // all waves done reading a_lds
#pragma unroll
      for (int fr = 0; fr < 2; ++fr)
#pragma unroll
        for (int fc = 0; fc < 2; ++fc)
#pragma unroll
          for (int j = 0; j < 4; ++j) {
            int fcol = wc * 32 + fc * 16 + c16;     // 0..63 (local dv)
            int m = wr * 32 + fr * 16 + g * 4 + j;  // 0..63 (local s)
            a_lds[fcol * 72 + m] = f2bf(acc[fr][fc][j]);
          }
      __syncthreads();
      const int b = mt >> 4, sl0 = m0 & 1023;
      const int hq = nt >> 1, dvb = (nt & 1) * 64;
#pragma unroll
      for (int i = 0; i < 2; ++i) {
        int r = tid >> 2, c0 = ((tid & 3) * 2 + i) * 8;   // r 0..63, c0 0..56
        bf8_t v = *reinterpret_cast<const bf8_t*>(&a_lds[r * 72 + c0]);
        size_t adr = ((size_t)((b * 16 + hq) * 128 + dvb + r)) * 1024 + sl0 + c0;
        *reinterpret_cast<bf8_t*>(vo + adr) = v;
      }
    } else {
      // ---- q/k: RoPE epilogue (tables [p][s], f4 loads) ----
      u16* outp = (mat == 0) ? qo : ko;
#pragma unroll
      for (int fr = 0; fr < 2; ++fr) {
#pragma unroll
        for (int fc = 0; fc < 2; ++fc) {
          int fcol = n0 + wc * 32 + fc * 16 + c16;   // 0..2047
          int h = fcol >> 7, d = fcol & 127, p = d >> 1;
          int m_base = m0 + wr * 32 + fr * 16 + g * 4;
          int b = m_base >> 10, sl_base = m_base & 1023;
          f4_t cv4 = *reinterpret_cast<const f4_t*>(&cosT[p * 1024 + sl_base]);
          f4_t sv4 = *reinterpret_cast<const f4_t*>(&sinT[p * 1024 + sl_base]);
#pragma unroll
          for (int j = 0; j < 4; ++j) {
            float v = acc[fr][fc][j];
            float vx = __shfl_xor(v, 1);
            float cv = cv4[j], sv = sv4[j];
            if (!(lane & 1)) {
              float e_out = v * cv - vx * sv;
              float o_out = v * sv + vx * cv;
              u32 u = (u32)f2bf(e_out) | ((u32)f2bf(o_out) << 16);
              u32 elem = ((u32)((b * 16 + h) * 1024 + (sl_base + j))) * 128 + (u32)d;
              reinterpret_cast<u32*>(outp)[elem >> 1] = u;
            }
          }
        }
      }
    }
  }
}

// ---------------- kernel B: flash attention (round-9/11 proven, verbatim) --
// 4 waves x 16 q-rows; qt = 2pp + (wid>>1); T = pp+1 KV tiles of 64. l via
// ones-column (vT row 128). Defer-max guard. 12 waves/CU.
__device__ __forceinline__ void stage_kv(const u16* __restrict__ Kp,
                                         const u16* __restrict__ Vt, int t,
                                         int tid, u16* k_lds, u16* vT) {
#pragma unroll
  for (int i = 0; i < 4; ++i) {
    int n = tid >> 2, c0 = ((tid & 3) * 4 + i) * 8;            // K: 64x128
    bf8_t kv = *reinterpret_cast<const bf8_t*>(Kp + (size_t)(t * 64 + n) * 128 + c0);
    *reinterpret_cast<bf8_t*>(&k_lds[n * 128 + (c0 ^ ((n & 7) << 3))]) = kv;
    int dv = tid >> 1, c1 = ((tid & 1) * 4 + i) * 8;           // vT: 128x64
    bf8_t vv = *reinterpret_cast<const bf8_t*>(Vt + (size_t)dv * 1024 + t * 64 + c1);
    *reinterpret_cast<bf8_t*>(&vT[dv * 72 + c1]) = vv;
  }
}

__global__ __launch_bounds__(256, 3) void attn(
    const u16* __restrict__ qw, const u16* __restrict__ kw,
    const u16* __restrict__ vtg, u16* __restrict__ yw) {
  __shared__ __align__(16) u16 k_lds[64 * 128];       // 16 KB, XOR swizzle
  __shared__ __align__(16) u16 vT[144 * 72];          // 20.25 KB, stride-72 pad
  __shared__ __align__(16) u16 p_lds[4][16 * 64];     // 8 KB, per-wave
  const int tid = threadIdx.x, lane = tid & 63, wid = tid >> 6;
  const int g = lane >> 4, c16 = lane & 15;
  const int bid = blockIdx.x;                  // 0..1023
  const int pp = 15 - (bid >> 6);              // LPT: long blocks first
  const int bh = bid & 63;                     // bid%8 == bh%8 -> same XCD
  const int b = bh >> 4, h = bh & 15;
  const int qt = 2 * pp + (wid >> 1);          // this wave-pair's 32-row q-tile
  const int T = pp + 1;
  const u16* Qp = qw + (size_t)bh * SEQ * DH;
  const u16* Kp = kw + (size_t)bh * SEQ * DH;
  const u16* Vt = vtg + (size_t)bh * DH * SEQ;
  const float kscale = 0.08838834764831845f * 1.4426950408889634f; // rsqrt(128)*log2e
  const int qrow0 = qt * 32 + (wid & 1) * 16;  // wave's 16 q-rows (global)
  const int moff = (wid >> 1) * 32 + (wid & 1) * 16;  // diag-mask offset

  // ones row (dv=128) + zero rows 129..143 (cols 0..63 read)
  {
    int r = 128 + (tid >> 4), c0 = (tid & 15) * 4;
    u16 v = (r == 128) ? (u16)0x3F80 : (u16)0;
#pragma unroll
    for (int e = 0; e < 4; ++e) vT[r * 72 + c0 + e] = v;
  }

  bf8_t qf[4];
#pragma unroll
  for (int c = 0; c < 4; ++c)
    qf[c] = *reinterpret_cast<const bf8_t*>(Qp + (size_t)(qrow0 + c16) * 128 + c * 32 + g * 8);

  f4_t yacc[9];                               // [8] = l (ones-column)
#pragma unroll
  for (int f = 0; f < 9; ++f) yacc[f] = (f4_t)0.0f;
  float m_run[4];
#pragma unroll
  for (int j = 0; j < 4; ++j) m_run[j] = -3e38f;

  stage_kv(Kp, Vt, 0, tid, k_lds, vT);
  __syncthreads();

  for (int t = 0; t < T; ++t) {
    // ---- S = Q K^T ----
    f4_t sf[4];
#pragma unroll
    for (int nf = 0; nf < 4; ++nf) sf[nf] = (f4_t)0.0f;
    __builtin_amdgcn_s_setprio(1);
#pragma unroll
    for (int nf = 0; nf < 4; ++nf) {
      int row = nf * 16 + c16;
#pragma unroll
      for (int kc = 0; kc < 4; ++kc) {
        int hw = ((row << 7) | (kc * 32 + g * 8)) ^ ((row & 7) << 3);
        bf8_t kf = *reinterpret_cast<const bf8_t*>(&k_lds[hw]);
        sf[nf] = __builtin_amdgcn_mfma_f32_16x16x32_bf16(qf[kc], kf, sf[nf], 0, 0, 0);
      }
    }
    __builtin_amdgcn_s_setprio(0);

    // ---- diagonal mask (last tile only) ----
    if (t == T - 1) {
#pragma unroll
      for (int nf = 0; nf < 4; ++nf) {
        int keyc = nf * 16 + c16;
#pragma unroll
        for (int j = 0; j < 4; ++j)
          if (keyc > moff + g * 4 + j) sf[nf][j] = -3e38f;
      }
    }

    // ---- defer-max guard: cross-lane work only when needed (tile 0 + rare)
    int chk = 0;
#pragma unroll
    for (int j = 0; j < 4; ++j) {
      float lmx = fmaxf(fmaxf(sf[0][j], sf[1][j]), fmaxf(sf[2][j], sf[3][j]));
      chk |= (lmx > m_run[j] + 32.0f) ? 1 : 0;
    }
    if (__any(chk)) {
      float lm[4];
#pragma unroll
      for (int j = 0; j < 4; ++j) {
        lm[j] = fmaxf(fmaxf(sf[0][j], sf[1][j]), fmaxf(sf[2][j], sf[3][j]));
        lm[j] = fmaxf(lm[j], __shfl_xor(lm[j], 1));
        lm[j] = fmaxf(lm[j], __shfl_xor(lm[j], 2));
        lm[j] = fmaxf(lm[j], __shfl_xor(lm[j], 4));
        lm[j] = fmaxf(lm[j], __shfl_xor(lm[j], 8));
      }
#pragma unroll
      for (int j = 0; j < 4; ++j) {
        float mn = fmaxf(m_run[j], lm[j]);
        float alpha = exp2f((m_run[j] - mn) * kscale);
        m_run[j] = mn;
#pragma unroll
        for (int f = 0; f < 9; ++f) yacc[f][j] *= alpha;
      }
    }

    // ---- P = exp2((S-m)*ks) -> bf16 -> wave-private p_lds ----
#pragma unroll
    for (int nf = 0; nf < 4; ++nf) {
#pragma unroll
      for (int j = 0; j < 4; ++j) {
        float pv = exp2f((sf[nf][j] - m_run[j]) * kscale);
        int q = g * 4 + j, n = nf * 16 + c16;
        int hw = ((q << 6) | n) ^ ((q & 7) << 3);
        p_lds[wid][hw] = f2bf(pv);
      }
    }
    bf8_t pa[2];
#pragma unroll
    for (int cc = 0; cc < 2; ++cc) {
      int hw = ((c16 << 6) | (cc * 32 + g * 8)) ^ ((c16 & 7) << 3);
      pa[cc] = *reinterpret_cast<const bf8_t*>(&p_lds[wid][hw]);
    }

    // ---- y += P V ; l accumulates via ones-column (f=8) ----
    __builtin_amdgcn_s_setprio(1);
#pragma unroll
    for (int f = 0; f < 9; ++f) {
#pragma unroll
      for (int cc = 0; cc < 2; ++cc) {
        bf8_t vf = *reinterpret_cast<const bf8_t*>(&vT[(f * 16 + c16) * 72 + cc * 32 + g * 8]);
        yacc[f] = __builtin_amdgcn_mfma_f32_16x16x32_bf16(pa[cc], vf, yacc[f], 0, 0, 0);
      }
    }
    __builtin_amdgcn_s_setprio(0);

    __syncthreads();                     // everyone done reading k/vT
    if (t + 1 < T) {
      stage_kv(Kp, Vt, t + 1, tid, k_lds, vT);
      __syncthreads();
    }
  }

  // ---- epilogue: l broadcast from c16==0 lane; y /= l; store bf16 ----
  float rl[4];
#pragma unroll
  for (int j = 0; j < 4; ++j) {
    float lv = __shfl(yacc[8][j], lane & 48);
    rl[j] = 1.0f / lv;
  }
#pragma unroll
  for (int f = 0; f < 8; ++f) {
#pragma unroll
    for (int j = 0; j < 4; ++j) {
      float yv = yacc[f][j] * rl[j];
      float yn = __shfl_xor(yv, 1);
      if (!(lane & 1)) {
        int s_ = qrow0 + g * 4 + j;
        int dv = f * 16 + c16;
        u32 u = (u32)f2bf(yv) | ((u32)f2bf(yn) << 16);
        u32 elem = ((u32)(b * 1024 + s_)) * 2048 + (u32)(h * 128 + dv);
        reinterpret_cast<u32*>(yw)[elem >> 1] = u;
      }
    }
  }
}

// ---------------- kernel C: output projection (split-K=2, T14 prefetch) ----
__global__ __launch_bounds__(256) void oproj(
    const u16* __restrict__ yw, const u16* __restrict__ wob,
    float* __restrict__ out) {
  __shared__ __align__(16) u16 a_lds[64 * 64];
  __shared__ __align__(16) u16 b_lds[64 * 64];
  const int tid = threadIdx.x, lane = tid & 63, wid = tid >> 6;
  const int g = lane >> 4, c16 = lane & 15;
  const int wr = wid >> 1, wc = wid & 1;
  const int m0 = blockIdx.x * 64, n0 = blockIdx.y * 64;
  const int z = blockIdx.z;
  const int kt0 = z * 16;
  f4_t acc[2][2];
#pragma unroll
  for (int a = 0; a < 2; ++a)
#pragma unroll
    for (int b = 0; b < 2; ++b) acc[a][b] = (f4_t)0.0f;

  const int srow = tid >> 3, sk0 = (tid & 7) * 8;

  bf8_t areg[2], breg[2];
#pragma unroll
  for (int i = 0; i < 2; ++i) {
    int row = srow + i * 32;
    areg[i] = *reinterpret_cast<const bf8_t*>(yw + (size_t)(m0 + row) * 2048 + kt0 * 64 + sk0);
    breg[i] = *reinterpret_cast<const bf8_t*>(wob + (size_t)(n0 + row) * 2048 + kt0 * 64 + sk0);
  }
#pragma unroll
  for (int i = 0; i < 2; ++i) {
    int row = srow + i * 32;
    int hw = ((row << 6) | sk0) ^ ((row & 7) << 3);
    *reinterpret_cast<bf8_t*>(&a_lds[hw]) = areg[i];
    *reinterpret_cast<bf8_t*>(&b_lds[hw]) = breg[i];
  }
  __syncthreads();

  for (int kt = kt0; kt < kt0 + 16; ++kt) {
    const bool pf = (kt + 1 < kt0 + 16);
    if (pf) {
      int kb = (kt + 1) * 64;
#pragma unroll
      for (int i = 0; i < 2; ++i) {
        int row = srow + i * 32;
        areg[i] = *reinterpret_cast<const bf8_t*>(yw + (size_t)(m0 + row) * 2048 + kb + sk0);
        breg[i] = *reinterpret_cast<const bf8_t*>(wob + (size_t)(n0 + row) * 2048 + kb + sk0);
      }
    }
#pragma unroll
    for (int c = 0; c < 2; ++c) {
      bf8_t af[2], bf_[2];
#pragma unroll
      for (int fr = 0; fr < 2; ++fr) {
        int row = wr * 32 + fr * 16 + c16;
        int hw = ((row << 6) | (c * 32 + g * 8)) ^ ((row & 7) << 3);
        af[fr] = *reinterpret_cast<const bf8_t*>(&a_lds[hw]);
      }
#pragma unroll
      for (int fc = 0; fc < 2; ++fc) {
        int row = wc * 32 + fc * 16 + c16;
        int hw = ((row << 6) | (c * 32 + g * 8)) ^ ((row & 7) << 3);
        bf_[fc] = *reinterpret_cast<const bf8_t*>(&b_lds[hw]);
      }
#pragma unroll
      for (int fr = 0; fr < 2; ++fr)
#pragma unroll
        for (int fc = 0; fc < 2; ++fc)
          acc[fr][fc] = __builtin_amdgcn_mfma_f32_16x16x32_bf16(af[fr], bf_[fc], acc[fr][fc], 0, 0, 0);
    }
    __syncthreads();
    if (pf) {
#pragma unroll
      for (int i = 0; i < 2; ++i) {
        int row = srow + i * 32;
        int hw = ((row << 6) | sk0) ^ ((row & 7) << 3);
        *reinterpret_cast<bf8_t*>(&a_lds[hw]) = areg[i];
        *reinterpret_cast<bf8_t*>(&b_lds[hw]) = breg[i];
      }
      __syncthreads();
    }
  }
#pragma unroll
  for (int fr = 0; fr < 2; ++fr)
#pragma unroll
    for (int fc = 0; fc < 2; ++fc)
#pragma unroll
      for (int j = 0; j < 4; ++j) {
        int m = m0 + wr * 32 + fr * 16 + g * 4 + j;
        int e = n0 + wc * 32 + fc * 16 + c16;
        atomicAdd(&out[(size_t)m * 128 + e], acc[fr][fc][j]);  // 2 addends: exact
      }
}

// ---------------------------------------------------------------------------
extern "C" void kernel_launch(void* const* d_in, const int* in_sizes, int n_in,
                              void* d_out, int out_size, void* d_ws, size_t ws_size,
                              hipStream_t stream) {
  const float* x  = (const float*)d_in[0];
  const float* wq = (const float*)d_in[1];
  const float* wk = (const float*)d_in[2];
  const float* wv = (const float*)d_in[3];
  const float* wo = (const float*)d_in[4];
  float* out = (float*)d_out;

  char* ws = (char*)d_ws;
  const size_t NEED = (512ull << 10) + 4ull * (16ull << 20) + (3ull << 20);
  if (ws_size < NEED) return;
  float* cosT = (float*)ws;                 // [p][s] transposed
  float* sinT = cosT + 64 * 1024;
  u16* qws = (u16*)(ws + (512 << 10));
  u16* kws = qws + (8u << 20);
  u16* vws = kws + (8u << 20);      // vT_g[bh][dv][s]
  u16* yws = vws + (8u << 20);
  u16* xb  = yws + (8u << 20);
  u16* wqb = xb  + (1u << 19);
  u16* wkb = wqb + (1u << 18);
  u16* wvb = wkb + (1u << 18);
  u16* wob = wvb + (1u << 18);

  hipMemsetAsync(d_out, 0, (size_t)out_size * sizeof(float), stream);
  prep<<<1024, 256, 0, stream>>>(x, wq, wk, wv, wo, xb, wqb, wkb, wvb, wob, cosT, sinT);
  qkv_rope<<<dim3(64, 32), 256, 0, stream>>>(xb, wqb, wkb, wvb, cosT, sinT, qws, kws, vws);
  attn<<<1024, 256, 0, stream>>>(qws, kws, vws, yws);
  oproj<<<dim3(64, 2, 2), 256, 0, stream>>>(yws, wob, out);
}

// Round 15
// 91.019 us; speedup vs baseline: 1.3112x; 1.0099x over previous
//
#include <hip/hip_runtime.h>

typedef unsigned short u16;
typedef unsigned int   u32;
typedef __attribute__((ext_vector_type(8))) short bf8_t;   // 8 bf16 (4 VGPR)
typedef __attribute__((ext_vector_type(4))) float f4_t;

#define SEQ   1024
#define NH    16
#define DH    128
#define BATCH 4
#define MROWS 4096      // BATCH*SEQ
#define FDIM  2048      // NH*DH

__device__ __forceinline__ u16 f2bf(float f) {
  union { float f; u32 u; } v; v.f = f;
  u32 u = v.u;
  u += 0x7fffu + ((u >> 16) & 1u);   // RNE
  return (u16)(u >> 16);
}

// ---------------- kernel P: bf16 convert + RoPE tables (merged) ------------
__global__ __launch_bounds__(256) void prep(
    const float* __restrict__ x,  const float* __restrict__ wq,
    const float* __restrict__ wk, const float* __restrict__ wv,
    const float* __restrict__ wo,
    u16* __restrict__ xb, u16* __restrict__ wqb, u16* __restrict__ wkb,
    u16* __restrict__ wvb, u16* __restrict__ wob,
    float* __restrict__ cosT, float* __restrict__ sinT) {
  const int gb = blockIdx.x;
  if (gb < 768) {
    int i = gb * 256 + threadIdx.x;   // 0..196607
    const float* s; u16* d; int o;
    if      (i <  65536) { s = x;  d = xb;  o = i; }
    else if (i <  98304) { s = wq; d = wqb; o = i - 65536; }
    else if (i < 131072) { s = wk; d = wkb; o = i - 98304; }
    else if (i < 163840) { s = wv; d = wvb; o = i - 131072; }
    else                 { s = wo; d = wob; o = i - 163840; }
    const f4_t* sp = reinterpret_cast<const f4_t*>(s + (size_t)o * 8);
    f4_t a = sp[0], b = sp[1];
    bf8_t pk;
#pragma unroll
    for (int j = 0; j < 4; ++j) { pk[j] = (short)f2bf(a[j]); pk[4 + j] = (short)f2bf(b[j]); }
    *reinterpret_cast<bf8_t*>(d + (size_t)o * 8) = pk;
  } else {
    int i = (gb - 768) * 256 + threadIdx.x;      // 65536 = 64*1024
    int p = i >> 10, s = i & 1023;               // [p][s]
    float ef = (float)(2 * p) / 128.0f;
    float angf = (float)pow(10000.0, (double)ef);
    float thf  = (float)s * angf;
    cosT[i] = cosf(thf);
    sinT[i] = sinf(thf);
  }
}

// ---------------- kernel A: fused QKV projection + RoPE --------------------
// One block per (mt,nt): x-tile staged ONCE, then mat loop {q,k,v} staging
// only w. q,k: RoPE'd [bh][s][d]; v: transposed to vT_g[bh][dv][s].
__device__ __forceinline__ void stage_tile(const u16* __restrict__ src,
                                           u16* __restrict__ dst, int tid) {
#pragma unroll
  for (int i = 0; i < 4; ++i) {
    int idx = tid + i * 256;            // 0..1023
    int row = idx >> 4, e0 = (idx & 15) * 8;
    int hw = ((row << 7) | e0) ^ ((row & 7) << 3);
    *reinterpret_cast<bf8_t*>(&dst[hw]) =
        *reinterpret_cast<const bf8_t*>(src + (size_t)row * 128 + e0);
  }
}

__global__ __launch_bounds__(256) void qkv_rope(
    const u16* __restrict__ xb,
    const u16* __restrict__ wqb, const u16* __restrict__ wkb,
    const u16* __restrict__ wvb,
    const float* __restrict__ cosT, const float* __restrict__ sinT,
    u16* __restrict__ qo, u16* __restrict__ ko, u16* __restrict__ vo) {
  __shared__ __align__(16) u16 a_lds[64 * 128];
  __shared__ __align__(16) u16 b_lds[64 * 128];
  const int tid = threadIdx.x;
  const int mt = blockIdx.x;            // 0..63
  const int nt = blockIdx.y;            // 0..31
  const int m0 = mt * 64, n0 = nt * 64;

  stage_tile(xb + (size_t)m0 * 128, a_lds, tid);

  const int lane = tid & 63, wid = tid >> 6;
  const int wr = wid >> 1, wc = wid & 1;
  const int g = lane >> 4, c16 = lane & 15;

#pragma unroll
  for (int mat = 0; mat < 3; ++mat) {
    if (mat) __syncthreads();           // prior MFMA done with b_lds
    const u16* w = (mat == 0) ? wqb : ((mat == 1) ? wkb : wvb);
    stage_tile(w + (size_t)n0 * 128, b_lds, tid);
    __syncthreads();

    f4_t acc[2][2];
#pragma unroll
    for (int a = 0; a < 2; ++a)
#pragma unroll
      for (int b = 0; b < 2; ++b) acc[a][b] = (f4_t)0.0f;

#pragma unroll
    for (int kc = 0; kc < 4; ++kc) {
      bf8_t af[2], bf_[2];
#pragma unroll
      for (int fr = 0; fr < 2; ++fr) {
        int row = wr * 32 + fr * 16 + c16;
        int hw = ((row << 7) | (kc * 32 + g * 8)) ^ ((row & 7) << 3);
        af[fr] = *reinterpret_cast<const bf8_t*>(&a_lds[hw]);
      }
#pragma unroll
      for (int fc = 0; fc < 2; ++fc) {
        int row = wc * 32 + fc * 16 + c16;
        int hw = ((row << 7) | (kc * 32 + g * 8)) ^ ((row & 7) << 3);
        bf_[fc] = *reinterpret_cast<const bf8_t*>(&b_lds[hw]);
      }
#pragma unroll
      for (int fr = 0; fr < 2; ++fr)
#pragma unroll
        for (int fc = 0; fc < 2; ++fc)
          acc[fr][fc] = __builtin_amdgcn_mfma_f32_16x16x32_bf16(af[fr], bf_[fc], acc[fr][fc], 0, 0, 0);
    }

    if (mat == 2) {
      // ---- V: transpose via LDS (stride 72), write vT_g coalesced ----
      __syncthreads();                  // all waves done reading a_lds
#pragma unroll
      for (int fr = 0; fr < 2; ++fr)
#pragma unroll
        for (int fc = 0; fc < 2; ++fc)
#pragma unroll
          for (int j = 0; j < 4; ++j) {
            int fcol = wc * 32 + fc * 16 + c16;     // 0..63 (local dv)
            int m = wr * 32 + fr * 16 + g * 4 + j;  // 0..63 (local s)
            a_lds[fcol * 72 + m] = f2bf(acc[fr][fc][j]);
          }
      __syncthreads();
      const int b = mt >> 4, sl0 = m0 & 1023;
      const int hq = nt >> 1, dvb = (nt & 1) * 64;
#pragma unroll
      for (int i = 0; i < 2; ++i) {
        int r = tid >> 2, c0 = ((tid & 3) * 2 + i) * 8;   // r 0..63, c0 0..56
        bf8_t v = *reinterpret_cast<const bf8_t*>(&a_lds[r * 72 + c0]);
        size_t adr = ((size_t)((b * 16 + hq) * 128 + dvb + r)) * 1024 + sl0 + c0;
        *reinterpret_cast<bf8_t*>(vo + adr) = v;
      }
    } else {
      // ---- q/k: RoPE epilogue (tables [p][s], f4 loads) ----
      u16* outp = (mat == 0) ? qo : ko;
#pragma unroll
      for (int fr = 0; fr < 2; ++fr) {
#pragma unroll
        for (int fc = 0; fc < 2; ++fc) {
          int fcol = n0 + wc * 32 + fc * 16 + c16;   // 0..2047
          int h = fcol >> 7, d = fcol & 127, p = d >> 1;
          int m_base = m0 + wr * 32 + fr * 16 + g * 4;
          int b = m_base >> 10, sl_base = m_base & 1023;
          f4_t cv4 = *reinterpret_cast<const f4_t*>(&cosT[p * 1024 + sl_base]);
          f4_t sv4 = *reinterpret_cast<const f4_t*>(&sinT[p * 1024 + sl_base]);
#pragma unroll
          for (int j = 0; j < 4; ++j) {
            float v = acc[fr][fc][j];
            float vx = __shfl_xor(v, 1);
            float cv = cv4[j], sv = sv4[j];
            if (!(lane & 1)) {
              float e_out = v * cv - vx * sv;
              float o_out = v * sv + vx * cv;
              u32 u = (u32)f2bf(e_out) | ((u32)f2bf(o_out) << 16);
              u32 elem = ((u32)((b * 16 + h) * 1024 + (sl_base + j))) * 128 + (u32)d;
              reinterpret_cast<u32*>(outp)[elem >> 1] = u;
            }
          }
        }
      }
    }
  }
}

// ---------------- kernel B: flash attention (round-9/11 proven, verbatim) --
// 4 waves x 16 q-rows; qt = 2pp + (wid>>1); T = pp+1 KV tiles of 64. l via
// ones-column (vT row 128). Defer-max guard. 12 waves/CU.
__device__ __forceinline__ void stage_kv(const u16* __restrict__ Kp,
                                         const u16* __restrict__ Vt, int t,
                                         int tid, u16* k_lds, u16* vT) {
#pragma unroll
  for (int i = 0; i < 4; ++i) {
    int n = tid >> 2, c0 = ((tid & 3) * 4 + i) * 8;            // K: 64x128
    bf8_t kv = *reinterpret_cast<const bf8_t*>(Kp + (size_t)(t * 64 + n) * 128 + c0);
    *reinterpret_cast<bf8_t*>(&k_lds[n * 128 + (c0 ^ ((n & 7) << 3))]) = kv;
    int dv = tid >> 1, c1 = ((tid & 1) * 4 + i) * 8;           // vT: 128x64
    bf8_t vv = *reinterpret_cast<const bf8_t*>(Vt + (size_t)dv * 1024 + t * 64 + c1);
    *reinterpret_cast<bf8_t*>(&vT[dv * 72 + c1]) = vv;
  }
}

__global__ __launch_bounds__(256, 3) void attn(
    const u16* __restrict__ qw, const u16* __restrict__ kw,
    const u16* __restrict__ vtg, u16* __restrict__ yw) {
  __shared__ __align__(16) u16 k_lds[64 * 128];       // 16 KB, XOR swizzle
  __shared__ __align__(16) u16 vT[144 * 72];          // 20.25 KB, stride-72 pad
  __shared__ __align__(16) u16 p_lds[4][16 * 64];     // 8 KB, per-wave
  const int tid = threadIdx.x, lane = tid & 63, wid = tid >> 6;
  const int g = lane >> 4, c16 = lane & 15;
  const int bid = blockIdx.x;                  // 0..1023
  const int pp = 15 - (bid >> 6);              // LPT: long blocks first
  const int bh = bid & 63;                     // bid%8 == bh%8 -> same XCD
  const int b = bh >> 4, h = bh & 15;
  const int qt = 2 * pp + (wid >> 1);          // this wave-pair's 32-row q-tile
  const int T = pp + 1;
  const u16* Qp = qw + (size_t)bh * SEQ * DH;
  const u16* Kp = kw + (size_t)bh * SEQ * DH;
  const u16* Vt = vtg + (size_t)bh * DH * SEQ;
  const float kscale = 0.08838834764831845f * 1.4426950408889634f; // rsqrt(128)*log2e
  const int qrow0 = qt * 32 + (wid & 1) * 16;  // wave's 16 q-rows (global)
  const int moff = (wid >> 1) * 32 + (wid & 1) * 16;  // diag-mask offset

  // ones row (dv=128) + zero rows 129..143 (cols 0..63 read)
  {
    int r = 128 + (tid >> 4), c0 = (tid & 15) * 4;
    u16 v = (r == 128) ? (u16)0x3F80 : (u16)0;
#pragma unroll
    for (int e = 0; e < 4; ++e) vT[r * 72 + c0 + e] = v;
  }

  bf8_t qf[4];
#pragma unroll
  for (int c = 0; c < 4; ++c)
    qf[c] = *reinterpret_cast<const bf8_t*>(Qp + (size_t)(qrow0 + c16) * 128 + c * 32 + g * 8);

  f4_t yacc[9];                               // [8] = l (ones-column)
#pragma unroll
  for (int f = 0; f < 9; ++f) yacc[f] = (f4_t)0.0f;
  float m_run[4];
#pragma unroll
  for (int j = 0; j < 4; ++j) m_run[j] = -3e38f;

  stage_kv(Kp, Vt, 0, tid, k_lds, vT);
  __syncthreads();

  for (int t = 0; t < T; ++t) {
    // ---- S = Q K^T ----
    f4_t sf[4];
#pragma unroll
    for (int nf = 0; nf < 4; ++nf) sf[nf] = (f4_t)0.0f;
    __builtin_amdgcn_s_setprio(1);
#pragma unroll
    for (int nf = 0; nf < 4; ++nf) {
      int row = nf * 16 + c16;
#pragma unroll
      for (int kc = 0; kc < 4; ++kc) {
        int hw = ((row << 7) | (kc * 32 + g * 8)) ^ ((row & 7) << 3);
        bf8_t kf = *reinterpret_cast<const bf8_t*>(&k_lds[hw]);
        sf[nf] = __builtin_amdgcn_mfma_f32_16x16x32_bf16(qf[kc], kf, sf[nf], 0, 0, 0);
      }
    }
    __builtin_amdgcn_s_setprio(0);

    // ---- diagonal mask (last tile only) ----
    if (t == T - 1) {
#pragma unroll
      for (int nf = 0; nf < 4; ++nf) {
        int keyc = nf * 16 + c16;
#pragma unroll
        for (int j = 0; j < 4; ++j)
          if (keyc > moff + g * 4 + j) sf[nf][j] = -3e38f;
      }
    }

    // ---- defer-max guard: cross-lane work only when needed (tile 0 + rare)
    int chk = 0;
#pragma unroll
    for (int j = 0; j < 4; ++j) {
      float lmx = fmaxf(fmaxf(sf[0][j], sf[1][j]), fmaxf(sf[2][j], sf[3][j]));
      chk |= (lmx > m_run[j] + 32.0f) ? 1 : 0;
    }
    if (__any(chk)) {
      float lm[4];
#pragma unroll
      for (int j = 0; j < 4; ++j) {
        lm[j] = fmaxf(fmaxf(sf[0][j], sf[1][j]), fmaxf(sf[2][j], sf[3][j]));
        lm[j] = fmaxf(lm[j], __shfl_xor(lm[j], 1));
        lm[j] = fmaxf(lm[j], __shfl_xor(lm[j], 2));
        lm[j] = fmaxf(lm[j], __shfl_xor(lm[j], 4));
        lm[j] = fmaxf(lm[j], __shfl_xor(lm[j], 8));
      }
#pragma unroll
      for (int j = 0; j < 4; ++j) {
        float mn = fmaxf(m_run[j], lm[j]);
        float alpha = exp2f((m_run[j] - mn) * kscale);
        m_run[j] = mn;
#pragma unroll
        for (int f = 0; f < 9; ++f) yacc[f][j] *= alpha;
      }
    }

    // ---- P = exp2((S-m)*ks) -> bf16 -> wave-private p_lds ----
#pragma unroll
    for (int nf = 0; nf < 4; ++nf) {
#pragma unroll
      for (int j = 0; j < 4; ++j) {
        float pv = exp2f((sf[nf][j] - m_run[j]) * kscale);
        int q = g * 4 + j, n = nf * 16 + c16;
        int hw = ((q << 6) | n) ^ ((q & 7) << 3);
        p_lds[wid][hw] = f2bf(pv);
      }
    }
    bf8_t pa[2];
#pragma unroll
    for (int cc = 0; cc < 2; ++cc) {
      int hw = ((c16 << 6) | (cc * 32 + g * 8)) ^ ((c16 & 7) << 3);
      pa[cc] = *reinterpret_cast<const bf8_t*>(&p_lds[wid][hw]);
    }

    // ---- y += P V ; l accumulates via ones-column (f=8) ----
    __builtin_amdgcn_s_setprio(1);
#pragma unroll
    for (int f = 0; f < 9; ++f) {
#pragma unroll
      for (int cc = 0; cc < 2; ++cc) {
        bf8_t vf = *reinterpret_cast<const bf8_t*>(&vT[(f * 16 + c16) * 72 + cc * 32 + g * 8]);
        yacc[f] = __builtin_amdgcn_mfma_f32_16x16x32_bf16(pa[cc], vf, yacc[f], 0, 0, 0);
      }
    }
    __builtin_amdgcn_s_setprio(0);

    __syncthreads();                     // everyone done reading k/vT
    if (t + 1 < T) {
      stage_kv(Kp, Vt, t + 1, tid, k_lds, vT);
      __syncthreads();
    }
  }

  // ---- epilogue: l broadcast from c16==0 lane; y /= l; store bf16 ----
  float rl[4];
#pragma unroll
  for (int j = 0; j < 4; ++j) {
    float lv = __shfl(yacc[8][j], lane & 48);
    rl[j] = 1.0f / lv;
  }
#pragma unroll
  for (int f = 0; f < 8; ++f) {
#pragma unroll
    for (int j = 0; j < 4; ++j) {
      float yv = yacc[f][j] * rl[j];
      float yn = __shfl_xor(yv, 1);
      if (!(lane & 1)) {
        int s_ = qrow0 + g * 4 + j;
        int dv = f * 16 + c16;
        u32 u = (u32)f2bf(yv) | ((u32)f2bf(yn) << 16);
        u32 elem = ((u32)(b * 1024 + s_)) * 2048 + (u32)(h * 128 + dv);
        reinterpret_cast<u32*>(yw)[elem >> 1] = u;
      }
    }
  }
}

// ---------------- kernel C: output projection (split-K=2, true dbuf) -------
// Double-buffered LDS + reg prefetch: ONE barrier per K-iter. While MFMAing
// on buf[cur], prefetched regs are written to buf[cur^1] (no reader until
// after the barrier) -> race-free with a single sync.
__global__ __launch_bounds__(256) void oproj(
    const u16* __restrict__ yw, const u16* __restrict__ wob,
    float* __restrict__ out) {
  __shared__ __align__(16) u16 a_lds[2][64 * 64];
  __shared__ __align__(16) u16 b_lds[2][64 * 64];
  const int tid = threadIdx.x, lane = tid & 63, wid = tid >> 6;
  const int g = lane >> 4, c16 = lane & 15;
  const int wr = wid >> 1, wc = wid & 1;
  const int m0 = blockIdx.x * 64, n0 = blockIdx.y * 64;
  const int z = blockIdx.z;
  const int kt0 = z * 16;
  f4_t acc[2][2];
#pragma unroll
  for (int a = 0; a < 2; ++a)
#pragma unroll
    for (int b = 0; b < 2; ++b) acc[a][b] = (f4_t)0.0f;

  const int srow = tid >> 3, sk0 = (tid & 7) * 8;
  const int shw0 = ((srow << 6) | sk0) ^ ((srow & 7) << 3);
  const int shw1 = (((srow + 32) << 6) | sk0) ^ ((srow & 7) << 3);

  // prologue: stage kt0 into buf 0
  {
    bf8_t a0 = *reinterpret_cast<const bf8_t*>(yw + (size_t)(m0 + srow) * 2048 + kt0 * 64 + sk0);
    bf8_t a1 = *reinterpret_cast<const bf8_t*>(yw + (size_t)(m0 + srow + 32) * 2048 + kt0 * 64 + sk0);
    bf8_t b0 = *reinterpret_cast<const bf8_t*>(wob + (size_t)(n0 + srow) * 2048 + kt0 * 64 + sk0);
    bf8_t b1 = *reinterpret_cast<const bf8_t*>(wob + (size_t)(n0 + srow + 32) * 2048 + kt0 * 64 + sk0);
    *reinterpret_cast<bf8_t*>(&a_lds[0][shw0]) = a0;
    *reinterpret_cast<bf8_t*>(&a_lds[0][shw1]) = a1;
    *reinterpret_cast<bf8_t*>(&b_lds[0][shw0]) = b0;
    *reinterpret_cast<bf8_t*>(&b_lds[0][shw1]) = b1;
  }
  __syncthreads();

  for (int it = 0; it < 16; ++it) {
    const int cur = it & 1;
    const bool pf = (it + 1 < 16);
    bf8_t a0, a1, b0, b1;
    if (pf) {
      int kb = (kt0 + it + 1) * 64;
      a0 = *reinterpret_cast<const bf8_t*>(yw + (size_t)(m0 + srow) * 2048 + kb + sk0);
      a1 = *reinterpret_cast<const bf8_t*>(yw + (size_t)(m0 + srow + 32) * 2048 + kb + sk0);
      b0 = *reinterpret_cast<const bf8_t*>(wob + (size_t)(n0 + srow) * 2048 + kb + sk0);
      b1 = *reinterpret_cast<const bf8_t*>(wob + (size_t)(n0 + srow + 32) * 2048 + kb + sk0);
    }
#pragma unroll
    for (int c = 0; c < 2; ++c) {
      bf8_t af[2], bf_[2];
#pragma unroll
      for (int fr = 0; fr < 2; ++fr) {
        int row = wr * 32 + fr * 16 + c16;
        int hw = ((row << 6) | (c * 32 + g * 8)) ^ ((row & 7) << 3);
        af[fr] = *reinterpret_cast<const bf8_t*>(&a_lds[cur][hw]);
      }
#pragma unroll
      for (int fc = 0; fc < 2; ++fc) {
        int row = wc * 32 + fc * 16 + c16;
        int hw = ((row << 6) | (c * 32 + g * 8)) ^ ((row & 7) << 3);
        bf_[fc] = *reinterpret_cast<const bf8_t*>(&b_lds[cur][hw]);
      }
#pragma unroll
      for (int fr = 0; fr < 2; ++fr)
#pragma unroll
        for (int fc = 0; fc < 2; ++fc)
          acc[fr][fc] = __builtin_amdgcn_mfma_f32_16x16x32_bf16(af[fr], bf_[fc], acc[fr][fc], 0, 0, 0);
    }
    if (pf) {
      *reinterpret_cast<bf8_t*>(&a_lds[cur ^ 1][shw0]) = a0;
      *reinterpret_cast<bf8_t*>(&a_lds[cur ^ 1][shw1]) = a1;
      *reinterpret_cast<bf8_t*>(&b_lds[cur ^ 1][shw0]) = b0;
      *reinterpret_cast<bf8_t*>(&b_lds[cur ^ 1][shw1]) = b1;
    }
    __syncthreads();
  }
#pragma unroll
  for (int fr = 0; fr < 2; ++fr)
#pragma unroll
    for (int fc = 0; fc < 2; ++fc)
#pragma unroll
      for (int j = 0; j < 4; ++j) {
        int m = m0 + wr * 32 + fr * 16 + g * 4 + j;
        int e = n0 + wc * 32 + fc * 16 + c16;
        atomicAdd(&out[(size_t)m * 128 + e], acc[fr][fc][j]);  // 2 addends: exact
      }
}

// ---------------------------------------------------------------------------
extern "C" void kernel_launch(void* const* d_in, const int* in_sizes, int n_in,
                              void* d_out, int out_size, void* d_ws, size_t ws_size,
                              hipStream_t stream) {
  const float* x  = (const float*)d_in[0];
  const float* wq = (const float*)d_in[1];
  const float* wk = (const float*)d_in[2];
  const float* wv = (const float*)d_in[3];
  const float* wo = (const float*)d_in[4];
  float* out = (float*)d_out;

  char* ws = (char*)d_ws;
  const size_t NEED = (512ull << 10) + 4ull * (16ull << 20) + (3ull << 20);
  if (ws_size < NEED) return;
  float* cosT = (float*)ws;                 // [p][s] transposed
  float* sinT = cosT + 64 * 1024;
  u16* qws = (u16*)(ws + (512 << 10));
  u16* kws = qws + (8u << 20);
  u16* vws = kws + (8u << 20);      // vT_g[bh][dv][s]
  u16* yws = vws + (8u << 20);
  u16* xb  = yws + (8u << 20);
  u16* wqb = xb  + (1u << 19);
  u16* wkb = wqb + (1u << 18);
  u16* wvb = wkb + (1u << 18);
  u16* wob = wvb + (1u << 18);

  hipMemsetAsync(d_out, 0, (size_t)out_size * sizeof(float), stream);
  prep<<<1024, 256, 0, stream>>>(x, wq, wk, wv, wo, xb, wqb, wkb, wvb, wob, cosT, sinT);
  qkv_rope<<<dim3(64, 32), 256, 0, stream>>>(xb, wqb, wkb, wvb, cosT, sinT, qws, kws, vws);
  attn<<<1024, 256, 0, stream>>>(qws, kws, vws, yws);
  oproj<<<dim3(64, 2, 2), 256, 0, stream>>>(yws, wob, out);
}